// Round 3
// baseline (94.159 us; speedup 1.0000x reference)
//
#include <hip/hip_runtime.h>

#define NBINS 256
#define TPB 128           // 2 waves per block
#define RSTRIDE 260       // bytes per thread region: 256 bins + dummy(256) + pad; 65 dwords
#define RSTRIDE_DW 65

__global__ void zero_out_kernel(float* __restrict__ out) {
    out[threadIdx.x] = 0.0f;
}

__global__ __launch_bounds__(TPB) void hist_kernel(const float* __restrict__ x,
                                                   float* __restrict__ ws,
                                                   int n) {
    __shared__ unsigned char lh[TPB * RSTRIDE];   // 33280 B -> 4 blocks/CU
    unsigned int* lh32 = (unsigned int*)lh;
    const int tid = threadIdx.x;
    unsigned char* __restrict__ reg = &lh[tid * RSTRIDE];

    for (int i = tid; i < TPB * RSTRIDE_DW; i += TPB) lh32[i] = 0;
    __syncthreads();

    const int gid    = blockIdx.x * TPB + tid;
    const int stride = gridDim.x * TPB;
    const int n4     = n >> 2;
    const float4* __restrict__ x4 = (const float4*)x;

    // Depth-2 pipelined byte RMW chain. Read(e+1) is issued BEFORE write(e);
    // the only hazard is b_{e+1}==b_e (stale read), fixed by one select.
    // Bin math bit-matches reference: (f+4.0f) rounds once, *32.0f exact
    // (pow2), trunc==floor for >=0, x==4 -> 256 -> clamp 255, NaN/out-of-range
    // -> dummy slot 256 (never flushed). No fma contraction possible in
    // (f+4)*32 shape.
    int cur_b = 256;       // start chain on dummy slot
    unsigned int cur_v = 0;  // lh just zeroed

#define PROC(f) {                                              \
        float _s  = (f) + 4.0f;                                \
        float _t  = _s * 32.0f;                                \
        bool  _ok = ((f) >= -4.0f) & ((f) <= 4.0f);            \
        int   _b  = (int)_t;                                   \
        _b = _b > 255 ? 255 : _b;                              \
        _b = _ok ? _b : 256;                                   \
        unsigned int _nv = reg[_b];                            \
        reg[cur_b] = (unsigned char)(cur_v + 1u);              \
        cur_v = (_b == cur_b) ? cur_v + 1u : _nv;              \
        cur_b = _b;                                            \
    }

    int i = gid;
    for (; i + 3 * stride < n4; i += 4 * stride) {
        float4 a = x4[i];
        float4 b = x4[i + stride];
        float4 c = x4[i + 2 * stride];
        float4 d = x4[i + 3 * stride];
        PROC(a.x) PROC(a.y) PROC(a.z) PROC(a.w)
        PROC(b.x) PROC(b.y) PROC(b.z) PROC(b.w)
        PROC(c.x) PROC(c.y) PROC(c.z) PROC(c.w)
        PROC(d.x) PROC(d.y) PROC(d.z) PROC(d.w)
    }
    for (; i < n4; i += stride) {
        float4 a = x4[i];
        PROC(a.x) PROC(a.y) PROC(a.z) PROC(a.w)
    }
    for (int j = (n4 << 2) + gid; j < n; j += stride) {
        float f = x[j];
        PROC(f)
    }
#undef PROC
    // commit last pending element (dummy write if no elements: harmless)
    reg[cur_b] = (unsigned char)(cur_v + 1u);

    __syncthreads();

    // Flush: dword-column sums. Thread (h=tid>>6, c=tid&63) sums regions
    // t in [h*64, h*64+64) at dword column c (bins 4c..4c+3). Lane addresses
    // are consecutive dwords -> conflict-free.
    const int c = tid & 63;
    const int h = tid >> 6;
    unsigned s0 = 0, s1 = 0, s2 = 0, s3 = 0;
    for (int k = 0; k < 64; ++k) {
        unsigned v = lh32[(h * 64 + k) * RSTRIDE_DW + c];
        s0 += v & 0xFFu;
        s1 += (v >> 8) & 0xFFu;
        s2 += (v >> 16) & 0xFFu;
        s3 += v >> 24;
    }
    __syncthreads();
    if (h == 1) {
        lh32[c * 4 + 0] = s0;
        lh32[c * 4 + 1] = s1;
        lh32[c * 4 + 2] = s2;
        lh32[c * 4 + 3] = s3;
    }
    __syncthreads();
    if (h == 0) {
        s0 += lh32[c * 4 + 0];
        s1 += lh32[c * 4 + 1];
        s2 += lh32[c * 4 + 2];
        s3 += lh32[c * 4 + 3];
        float4 o;
        o.x = (float)s0; o.y = (float)s1; o.z = (float)s2; o.w = (float)s3;
        ((float4*)ws)[blockIdx.x * 64 + c] = o;   // 1 KB/block, coalesced
    }
}

__global__ __launch_bounds__(256) void reduce_kernel(const float* __restrict__ ws,
                                                     float* __restrict__ out,
                                                     int nblk) {
    const int tid = threadIdx.x;
    float s = 0.0f;
    for (int i = blockIdx.x; i < nblk; i += gridDim.x)
        s += ws[i * NBINS + tid];               // coalesced
    if (s != 0.0f)
        atomicAdd(&out[tid], s);                // integer-valued < 2^24: exact
}

extern "C" void kernel_launch(void* const* d_in, const int* in_sizes, int n_in,
                              void* d_out, int out_size, void* d_ws, size_t ws_size,
                              hipStream_t stream) {
    const float* x = (const float*)d_in[0];
    float* out = (float*)d_out;
    float* ws  = (float*)d_ws;
    const int n = in_sizes[0];

    const int n4 = n >> 2;
    // per-thread float4 quota 32 -> 128 elements/thread -> 8-bit counters safe
    long long want = ((long long)n4 + (long long)TPB * 32 - 1) / ((long long)TPB * 32);
    int blocks = (int)(want < 1 ? 1 : want);
    long long ws_cap = (long long)(ws_size / (NBINS * sizeof(float)));
    if (blocks > ws_cap) blocks = (int)ws_cap;

    hist_kernel<<<blocks, TPB, 0, stream>>>(x, ws, n);
    zero_out_kernel<<<1, NBINS, 0, stream>>>(out);

    int rblocks = blocks < 64 ? blocks : 64;
    reduce_kernel<<<rblocks, NBINS, 0, stream>>>(ws, out, blocks);
}

// Round 5
// 79.288 us; speedup vs baseline: 1.1876x; 1.1876x over previous
//
#include <hip/hip_runtime.h>

#define NBINS 256
#define TPB 256
#define NCOPY 4       // one copy per wave
#define CSTRIDE 264   // 256 bins + dummy slot(256) + pad; copies bank-rotate by 8

typedef float f32x4 __attribute__((ext_vector_type(4)));

__global__ void zero_out_kernel(float* __restrict__ out) {
    out[threadIdx.x] = 0.0f;
}

__global__ __launch_bounds__(TPB) void hist_kernel(const float* __restrict__ x,
                                                   float* __restrict__ out,
                                                   int n) {
    __shared__ int lh[NCOPY * CSTRIDE];   // 4224 B
    const int tid = threadIdx.x;
    int* __restrict__ myh = &lh[(tid >> 6) * CSTRIDE];

    for (int i = tid; i < NCOPY * CSTRIDE; i += TPB)
        lh[i] = 0;
    __syncthreads();

    const int gid    = blockIdx.x * TPB + tid;
    const int stride = gridDim.x * TPB;     // in float4 units
    const int n4     = n >> 2;
    const f32x4* __restrict__ x4 = (const f32x4*)x;

    // Branchless bin math, bit-identical to reference:
    //   ref computes fl(x+4) then exact /0.03125 (pow2) => fl(x+4)*32.
    //   (f+4.0f)*32.0f is add-then-mul of the SAME shape (not fma-contractible).
    //   trunc == floor for the non-negative in-range value; x==4 -> 256 -> 255;
    //   NaN / out-of-range -> dummy slot 256 (never flushed).
#define PROC(f) {                                        \
        float _t = ((f) + 4.0f) * 32.0f;                 \
        int   _b = (int)_t;                              \
        _b = _b > 255 ? 255 : _b;                        \
        bool _ok = ((f) >= -4.0f) & ((f) <= 4.0f);       \
        _b = _ok ? _b : 256;                             \
        atomicAdd(&myh[_b], 1);                          \
    }

    int i = gid;
    for (; i + 3 * stride < n4; i += 4 * stride) {
        f32x4 a = __builtin_nontemporal_load(&x4[i]);
        f32x4 b = __builtin_nontemporal_load(&x4[i + stride]);
        f32x4 c = __builtin_nontemporal_load(&x4[i + 2 * stride]);
        f32x4 d = __builtin_nontemporal_load(&x4[i + 3 * stride]);
        PROC(a.x) PROC(a.y) PROC(a.z) PROC(a.w)
        PROC(b.x) PROC(b.y) PROC(b.z) PROC(b.w)
        PROC(c.x) PROC(c.y) PROC(c.z) PROC(c.w)
        PROC(d.x) PROC(d.y) PROC(d.z) PROC(d.w)
    }
    for (; i < n4; i += stride) {
        f32x4 a = __builtin_nontemporal_load(&x4[i]);
        PROC(a.x) PROC(a.y) PROC(a.z) PROC(a.w)
    }
    for (int j = (n4 << 2) + gid; j < n; j += stride) {
        float f = x[j];
        PROC(f)
    }
#undef PROC

    __syncthreads();

    // flush: bin `tid` summed across the 4 wave copies (consecutive-int reads,
    // conflict-free); one float atomic per bin per block. Counts are
    // integer-valued < 2^24 -> float adds exact & order-independent.
    int s = lh[0 * CSTRIDE + tid] + lh[1 * CSTRIDE + tid] +
            lh[2 * CSTRIDE + tid] + lh[3 * CSTRIDE + tid];
    if (s)
        atomicAdd(&out[tid], (float)s);
}

extern "C" void kernel_launch(void* const* d_in, const int* in_sizes, int n_in,
                              void* d_out, int out_size, void* d_ws, size_t ws_size,
                              hipStream_t stream) {
    const float* x = (const float*)d_in[0];
    float* out = (float*)d_out;
    const int n = in_sizes[0];

    // d_out is poisoned before timing and not re-zeroed between replays:
    // zero it ourselves every call (stream-ordered before hist).
    zero_out_kernel<<<1, NBINS, 0, stream>>>(out);

    int n4 = n >> 2;
    long long want = ((long long)n4 + (long long)TPB * 4 - 1) / ((long long)TPB * 4);
    int blocks = (int)(want < 1 ? 1 : (want > 2048 ? 2048 : want));
    hist_kernel<<<blocks, TPB, 0, stream>>>(x, out, n);
}

// Round 6
// 76.817 us; speedup vs baseline: 1.2258x; 1.0322x over previous
//
#include <hip/hip_runtime.h>

#define NBINS 256
#define TPB 256
#define NCOPY 4       // one copy per wave
#define CSTRIDE 264   // 256 bins + dummy slot(256) + pad; copies bank-rotate by 8

typedef float f32x4 __attribute__((ext_vector_type(4)));

__global__ void zero_out_kernel(float* __restrict__ out) {
    out[threadIdx.x] = 0.0f;
}

__global__ __launch_bounds__(TPB) void hist_kernel(const float* __restrict__ x,
                                                   float* __restrict__ out,
                                                   int n) {
    __shared__ int lh[NCOPY * CSTRIDE];   // 4224 B
    const int tid = threadIdx.x;
    int* __restrict__ myh = &lh[(tid >> 6) * CSTRIDE];

    for (int i = tid; i < NCOPY * CSTRIDE; i += TPB)
        lh[i] = 0;
    __syncthreads();

    const int gid    = blockIdx.x * TPB + tid;
    const int stride = gridDim.x * TPB;     // in float4 units
    const int n4     = n >> 2;
    const f32x4* __restrict__ x4 = (const f32x4*)x;

    // Branchless bin math, bit-identical to reference:
    //   width = 8/256 = 0.03125 exact pow2 => floor((x-lo)/width) == trunc((x+4)*32)
    //   for in-range x (>=0); x==4 -> 256 -> clamp 255; NaN/out-of-range -> dummy
    //   slot 256 (never flushed). (f+4)*32 shape is not fma-contractible.
#define PROC(f) {                                        \
        float _t = ((f) + 4.0f) * 32.0f;                 \
        int   _b = (int)_t;                              \
        _b = _b > 255 ? 255 : _b;                        \
        bool _ok = ((f) >= -4.0f) & ((f) <= 4.0f);       \
        _b = _ok ? _b : 256;                             \
        atomicAdd(&myh[_b], 1);                          \
    }
#define PROC16(a, b, c, d) {                             \
        PROC(a.x) PROC(a.y) PROC(a.z) PROC(a.w)          \
        PROC(b.x) PROC(b.y) PROC(b.z) PROC(b.w)          \
        PROC(c.x) PROC(c.y) PROC(c.z) PROC(c.w)          \
        PROC(d.x) PROC(d.y) PROC(d.z) PROC(d.w)          \
    }

    // Wave-uniform full-iteration count: each iteration consumes 4 float4s
    // per thread at [i, i+stride, i+2*stride, i+3*stride], i += 4*stride.
    const int iters = n4 / (4 * stride);   // uniform across all threads

    // Depth-2 software pipeline: next iteration's 4 loads are issued BEFORE
    // processing the current 4 float4s, so VMEM is in flight during the
    // atomic/VALU body regardless of compiler scheduling.
    if (iters > 0) {
        int i = gid;
        f32x4 a = __builtin_nontemporal_load(&x4[i]);
        f32x4 b = __builtin_nontemporal_load(&x4[i + stride]);
        f32x4 c = __builtin_nontemporal_load(&x4[i + 2 * stride]);
        f32x4 d = __builtin_nontemporal_load(&x4[i + 3 * stride]);
        for (int t = 1; t < iters; ++t) {
            const int ni = i + 4 * stride;
            f32x4 na = __builtin_nontemporal_load(&x4[ni]);
            f32x4 nb = __builtin_nontemporal_load(&x4[ni + stride]);
            f32x4 nc = __builtin_nontemporal_load(&x4[ni + 2 * stride]);
            f32x4 nd = __builtin_nontemporal_load(&x4[ni + 3 * stride]);
            PROC16(a, b, c, d)
            a = na; b = nb; c = nc; d = nd;
            i = ni;
        }
        PROC16(a, b, c, d)
    }

    // leftover float4s beyond the uniform region
    for (int i = iters * 4 * stride + gid; i < n4; i += stride) {
        f32x4 a = __builtin_nontemporal_load(&x4[i]);
        PROC(a.x) PROC(a.y) PROC(a.z) PROC(a.w)
    }
    // scalar tail (n % 4 != 0 — not hit for N=64M)
    for (int j = (n4 << 2) + gid; j < n; j += stride) {
        float f = x[j];
        PROC(f)
    }
#undef PROC16
#undef PROC

    __syncthreads();

    // flush: bin `tid` summed across the 4 wave copies (consecutive-int reads,
    // conflict-free); one float atomic per bin per block. Counts are
    // integer-valued < 2^24 -> float adds exact & order-independent.
    int s = lh[0 * CSTRIDE + tid] + lh[1 * CSTRIDE + tid] +
            lh[2 * CSTRIDE + tid] + lh[3 * CSTRIDE + tid];
    if (s)
        atomicAdd(&out[tid], (float)s);
}

extern "C" void kernel_launch(void* const* d_in, const int* in_sizes, int n_in,
                              void* d_out, int out_size, void* d_ws, size_t ws_size,
                              hipStream_t stream) {
    const float* x = (const float*)d_in[0];
    float* out = (float*)d_out;
    const int n = in_sizes[0];

    // d_out is poisoned before timing and not re-zeroed between replays:
    // zero it ourselves every call (stream-ordered before hist).
    zero_out_kernel<<<1, NBINS, 0, stream>>>(out);

    int n4 = n >> 2;
    long long want = ((long long)n4 + (long long)TPB * 4 - 1) / ((long long)TPB * 4);
    int blocks = (int)(want < 1 ? 1 : (want > 2048 ? 2048 : want));
    hist_kernel<<<blocks, TPB, 0, stream>>>(x, out, n);
}